// Round 15
// baseline (419.720 us; speedup 1.0000x reference)
//
#include <hip/hip_runtime.h>
#include <hip/hip_bf16.h>
#include <math.h>

#define B_   16
#define N_   2304
#define C_   768
#define H_   12
#define D_   64
#define M_   (B_*N_)      // 36864
#define NQKV 2496
#define NPAD 2560
#define CCP  832          // concat stride = 13 K-tiles of 64, exact
#define LDW  76           // inner-kernel LDS row stride (bank-conflict-free, R14)
#define EVS  (-1.0f/6912.0f)   // -SCALE/N = -(1/3)/2304

typedef __bf16 bf16x8 __attribute__((ext_vector_type(8)));
typedef __bf16 bf16x4 __attribute__((ext_vector_type(4)));
typedef float  f32x4  __attribute__((ext_vector_type(4)));

static __device__ __forceinline__ void gload_lds16(const void* g, void* l) {
  __builtin_amdgcn_global_load_lds((const __attribute__((address_space(1))) void*)g,
                                   (__attribute__((address_space(3))) void*)l, 16, 0, 0);
}

static __device__ __forceinline__ bf16x8 ld8(const __bf16* p) {
  bf16x4 lo = *(const bf16x4*)p;
  bf16x4 hi = *(const bf16x4*)(p + 4);
  return __builtin_shufflevector(lo, hi, 0,1,2,3,4,5,6,7);
}

// ---------------- converts: weights only (x is consumed f32 by gemmXF) -------------
__global__ __launch_bounds__(256) void cvt_all(
    const float* __restrict__ qkv_w, const float* __restrict__ qkv_b,
    const float* __restrict__ proj_w,
    __bf16* __restrict__ wqkvb, float* __restrict__ qkvbp, __bf16* __restrict__ pwb)
{
  const int blk = blockIdx.x;
  if (blk < 960) {
    int i = blk * 256 + threadIdx.x;   // [0, 245760)
    int n = i / 96, c8 = i - n * 96;
    bf16x8 o;
    if (n < NQKV) {
      const float4* p = (const float4*)(qkv_w + (size_t)n * 768 + c8 * 8);
      float4 a = p[0], b = p[1];
      o = (bf16x8){(__bf16)a.x,(__bf16)a.y,(__bf16)a.z,(__bf16)a.w,
                   (__bf16)b.x,(__bf16)b.y,(__bf16)b.z,(__bf16)b.w};
    } else {
      o = (bf16x8){(__bf16)0.f,(__bf16)0.f,(__bf16)0.f,(__bf16)0.f,
                   (__bf16)0.f,(__bf16)0.f,(__bf16)0.f,(__bf16)0.f};
    }
    *(bf16x8*)(wqkvb + (size_t)n * 768 + c8 * 8) = o;
    if (i < NPAD) qkvbp[i] = (i < NQKV) ? qkv_b[i] : 0.0f;
  } else {
    int i = (blk - 960) * 256 + threadIdx.x;   // [0, 79872)
    if (i >= 79872) return;
    const float4* p = (const float4*)(proj_w + (size_t)i * 8);
    float4 a = p[0], b = p[1];
    bf16x8 o = {(__bf16)a.x,(__bf16)a.y,(__bf16)a.z,(__bf16)a.w,
                (__bf16)b.x,(__bf16)b.y,(__bf16)b.z,(__bf16)b.w};
    *(bf16x8*)(pwb + (size_t)i * 8) = o;
  }
}

// ---------------- QKV GEMM: A read directly as f32 (fused convert) ------------------
// 256x256, BK=64, lead-1 dbuf, 1 __syncthreads per K-tile (R10-verified structure).
// A: reg-staged (issue f32 loads at loop top, cvt+ds_write after MFMA — T14).
// B: global_load_lds bf16. Same chunk-XOR swizzle both paths. 8 waves (2M x 4N).
__global__ __launch_bounds__(512, 1) void gemmXF(
    const float* __restrict__ A, const __bf16* __restrict__ Bt,
    const float* __restrict__ bias, __bf16* __restrict__ Cout,
    const int K, const int ldc, const int nbn, const int KT)
{
  __shared__ __align__(16) __bf16 sA[2][256 * 64];
  __shared__ __align__(16) __bf16 sB[2][256 * 64];
  const int tid  = threadIdx.x;
  const int lane = tid & 63;
  const int wid  = tid >> 6;
  const int wm = wid >> 2;       // 0..1
  const int wn = wid & 3;        // 0..3
  const int l15 = lane & 15, lq = lane >> 4;

  const int nwg = gridDim.x;
  const int swz = ((int)blockIdx.x & 7) * (nwg >> 3) + ((int)blockIdx.x >> 3);
  const int bm = swz / nbn;
  const int bn = swz - bm * nbn;

  const int strow  = tid >> 3;                          // 0..63
  const int stoff  = strow * 64 + (tid & 7) * 8;        // linear LDS dest (elems)
  const int schunk = ((tid & 7) ^ (strow & 7)) * 8;     // inverse-swizzled global chunk
  const float*  gA = A  + (size_t)((size_t)bm * 256 + strow) * K + schunk;
  const __bf16* gB = Bt + (size_t)((size_t)bn * 256 + strow) * K + schunk;

  f32x4 acc[2][4][2][2];
  #pragma unroll
  for (int a = 0; a < 2; ++a)
    #pragma unroll
    for (int m = 0; m < 4; ++m)
      #pragma unroll
      for (int b = 0; b < 2; ++b)
        #pragma unroll
        for (int n = 0; n < 2; ++n) acc[a][m][b][n] = (f32x4){0.f,0.f,0.f,0.f};

  float4 av[4][2];
  bf16x8 af0[4][2], af1[4][2], bf0[2][2], bf1[2][2];

#define A_ISSUE(T) do {                                                         \
    const size_t ko_ = (size_t)(T) * 64;                                        \
    _Pragma("unroll") for (int j_ = 0; j_ < 4; ++j_) {                          \
      const float* ap_ = gA + (size_t)(j_ * 64) * K + ko_;                      \
      av[j_][0] = *(const float4*)(ap_);                                        \
      av[j_][1] = *(const float4*)(ap_ + 4);                                    \
    } } while (0)
#define A_WRITE(q) do {                                                         \
    _Pragma("unroll") for (int j_ = 0; j_ < 4; ++j_) {                          \
      bf16x8 o_ = {(__bf16)av[j_][0].x,(__bf16)av[j_][0].y,                     \
                   (__bf16)av[j_][0].z,(__bf16)av[j_][0].w,                     \
                   (__bf16)av[j_][1].x,(__bf16)av[j_][1].y,                     \
                   (__bf16)av[j_][1].z,(__bf16)av[j_][1].w};                    \
      *(bf16x8*)&sA[q][j_ * 4096 + stoff] = o_;                                 \
    } } while (0)
#define B_STAGE(q, T) do {                                                      \
    const size_t ko_ = (size_t)(T) * 64;                                        \
    _Pragma("unroll") for (int j_ = 0; j_ < 4; ++j_)                            \
      gload_lds16(gB + (size_t)(j_ * 64) * K + ko_, &sB[q][j_ * 4096 + stoff]); \
  } while (0)
#define LOADA(DST, h, q) do {                                                   \
    _Pragma("unroll") for (int mf_ = 0; mf_ < 4; ++mf_) {                       \
      const int r_ = (h) * 128 + wm * 64 + mf_ * 16 + l15;                      \
      _Pragma("unroll") for (int kk_ = 0; kk_ < 2; ++kk_)                       \
        DST[mf_][kk_] = *(const bf16x8*)&sA[q][r_ * 64 + (((kk_*4+lq) ^ (r_&7)) * 8)]; \
    } } while (0)
#define LOADB(DST, h, q) do {                                                   \
    _Pragma("unroll") for (int nf_ = 0; nf_ < 2; ++nf_) {                       \
      const int c_ = (h) * 128 + wn * 32 + nf_ * 16 + l15;                      \
      _Pragma("unroll") for (int kk_ = 0; kk_ < 2; ++kk_)                       \
        DST[nf_][kk_] = *(const bf16x8*)&sB[q][c_ * 64 + (((kk_*4+lq) ^ (c_&7)) * 8)]; \
    } } while (0)
#define MMA(a_, b_, AF, BF) do {                                                \
    __builtin_amdgcn_s_setprio(1);                                              \
    _Pragma("unroll") for (int kk_ = 0; kk_ < 2; ++kk_)                         \
    _Pragma("unroll") for (int mf_ = 0; mf_ < 4; ++mf_)                         \
    _Pragma("unroll") for (int nf_ = 0; nf_ < 2; ++nf_)                         \
      acc[a_][mf_][b_][nf_] = __builtin_amdgcn_mfma_f32_16x16x32_bf16(          \
          AF[mf_][kk_], BF[nf_][kk_], acc[a_][mf_][b_][nf_], 0, 0, 0);          \
    __builtin_amdgcn_s_setprio(0);                                              \
  } while (0)

  // prologue: tile0 (A: load+cvt+write now; B: gload_lds)
  A_ISSUE(0);
  B_STAGE(0, 0);
  A_WRITE(0);
  __syncthreads();

  for (int t = 0; t < KT; ++t) {
    const int q = t & 1;
    if (t + 1 < KT) {
      A_ISSUE(t + 1);                 // f32 loads in flight across MFMA phase
      B_STAGE(q ^ 1, t + 1);          // into the OTHER buffer: no race
    }

    LOADB(bf0, 0, q); LOADB(bf1, 1, q);
    LOADA(af0, 0, q);
    MMA(0, 0, af0, bf0); MMA(0, 1, af0, bf1);
    LOADA(af1, 1, q);
    MMA(1, 0, af1, bf0); MMA(1, 1, af1, bf1);

    if (t + 1 < KT) {
      A_WRITE(q ^ 1);                 // loads are ~64 MFMAs old -> latency hidden
      __syncthreads();                // drains vmcnt (B gloads) + lgkmcnt (A writes)
    }
  }
#undef A_ISSUE
#undef A_WRITE
#undef B_STAGE
#undef LOADA
#undef LOADB
#undef MMA

  // epilogue: C write (+bias), bf16
  #pragma unroll
  for (int b = 0; b < 2; ++b)
    #pragma unroll
    for (int nf = 0; nf < 2; ++nf) {
      const int col = bn * 256 + b * 128 + wn * 32 + nf * 16 + l15;
      const float bs = bias[col];
      #pragma unroll
      for (int a = 0; a < 2; ++a)
        #pragma unroll
        for (int mf = 0; mf < 4; ++mf) {
          const int row0 = bm * 256 + a * 128 + wm * 64 + mf * 16 + lq * 4;
          #pragma unroll
          for (int r = 0; r < 4; ++r)
            Cout[(size_t)(row0 + r) * ldc + col] = (__bf16)(acc[a][mf][b][nf][r] + bs);
        }
    }
}

// ---------------- proj GEMM: 256x256, BK=64, 8-phase dbuf (frozen) ------------------
template<int OUTF32>
__global__ __launch_bounds__(512, 2) void gemm8(
    const __bf16* __restrict__ A, const __bf16* __restrict__ Bt,
    const float* __restrict__ bias, void* __restrict__ Cout,
    const int K, const int ldc, const int nbn, const int KT)
{
  __shared__ __align__(16) __bf16 sA[2][2][128 * 64];
  __shared__ __align__(16) __bf16 sB[2][2][128 * 64];
  const int tid  = threadIdx.x;
  const int lane = tid & 63;
  const int wid  = tid >> 6;
  const int wm = wid >> 2;       // 0..1
  const int wn = wid & 3;        // 0..3
  const int l15 = lane & 15, lq = lane >> 4;

  const int nwg = gridDim.x;
  const int swz = ((int)blockIdx.x & 7) * (nwg >> 3) + ((int)blockIdx.x >> 3);
  const int bm = swz / nbn;
  const int bn = swz - bm * nbn;

  const int strow = tid >> 3;                       // 0..63
  const int stoff = strow * 64 + (tid & 7) * 8;     // linear LDS dest (elements)
  const __bf16* gA = A  + (size_t)((size_t)bm * 256 + strow) * K + ((tid & 7) ^ (strow & 7)) * 8;
  const __bf16* gB = Bt + (size_t)((size_t)bn * 256 + strow) * K + ((tid & 7) ^ (strow & 7)) * 8;

  f32x4 acc[2][4][2][2];
  #pragma unroll
  for (int a = 0; a < 2; ++a)
    #pragma unroll
    for (int m = 0; m < 4; ++m)
      #pragma unroll
      for (int b = 0; b < 2; ++b)
        #pragma unroll
        for (int n = 0; n < 2; ++n) acc[a][m][b][n] = (f32x4){0.f,0.f,0.f,0.f};

  bf16x8 af0[4][2], af1[4][2], bf0[2][2], bf1[2][2];

#define STAGE_A(q, h, T) do {                                                   \
    const size_t ko_ = (size_t)(T) * 64;                                        \
    gload_lds16(gA + (size_t)((h)*128 +  0) * K + ko_, &sA[q][h][stoff]);       \
    gload_lds16(gA + (size_t)((h)*128 + 64) * K + ko_, &sA[q][h][4096 + stoff]);\
  } while (0)
#define STAGE_B(q, h, T) do {                                                   \
    const size_t ko_ = (size_t)(T) * 64;                                        \
    gload_lds16(gB + (size_t)((h)*128 +  0) * K + ko_, &sB[q][h][stoff]);       \
    gload_lds16(gB + (size_t)((h)*128 + 64) * K + ko_, &sB[q][h][4096 + stoff]);\
  } while (0)
#define LOADA(DST, h, q) do {                                                   \
    _Pragma("unroll") for (int mf_ = 0; mf_ < 4; ++mf_) {                       \
      const int r_ = wm * 64 + mf_ * 16 + l15;                                  \
      _Pragma("unroll") for (int kk_ = 0; kk_ < 2; ++kk_)                       \
        DST[mf_][kk_] = *(const bf16x8*)&sA[q][h][r_ * 64 + (((kk_*4+lq) ^ (r_&7)) * 8)]; \
    } } while (0)
#define LOADB(DST, h, q) do {                                                   \
    _Pragma("unroll") for (int nf_ = 0; nf_ < 2; ++nf_) {                       \
      const int c_ = wn * 32 + nf_ * 16 + l15;                                  \
      _Pragma("unroll") for (int kk_ = 0; kk_ < 2; ++kk_)                       \
        DST[nf_][kk_] = *(const bf16x8*)&sB[q][h][c_ * 64 + (((kk_*4+lq) ^ (c_&7)) * 8)]; \
    } } while (0)
#define MMA(a_, b_, AF, BF) do {                                                \
    __builtin_amdgcn_s_setprio(1);                                              \
    _Pragma("unroll") for (int kk_ = 0; kk_ < 2; ++kk_)                         \
    _Pragma("unroll") for (int mf_ = 0; mf_ < 4; ++mf_)                         \
    _Pragma("unroll") for (int nf_ = 0; nf_ < 2; ++nf_)                         \
      acc[a_][mf_][b_][nf_] = __builtin_amdgcn_mfma_f32_16x16x32_bf16(          \
          AF[mf_][kk_], BF[nf_][kk_], acc[a_][mf_][b_][nf_], 0, 0, 0);          \
    __builtin_amdgcn_s_setprio(0);                                              \
  } while (0)
#define BAR  __builtin_amdgcn_s_barrier()
#define VMW4 asm volatile("s_waitcnt vmcnt(4)" ::: "memory")
#define VMW0 asm volatile("s_waitcnt vmcnt(0)" ::: "memory")

  STAGE_A(0, 0, 0); STAGE_A(0, 1, 0); STAGE_B(0, 0, 0); STAGE_B(0, 1, 0);
  STAGE_B(1, 0, 1);
  STAGE_A(1, 1, 1);
  VMW4;
  BAR;

  for (int t = 0; t + 1 < KT; t += 2) {
    LOADA(af0, 0, 0); LOADB(bf0, 0, 0);
    STAGE_A(1, 0, t + 1); STAGE_B(1, 1, t + 1);
    BAR; MMA(0, 0, af0, bf0); BAR;
    LOADA(af1, 1, 0);
    BAR; MMA(1, 0, af1, bf0); BAR;
    LOADB(bf1, 1, 0);
    if (t + 2 < KT) STAGE_B(0, 0, t + 2);
    BAR; MMA(1, 1, af1, bf1); BAR;
    if (t + 2 < KT) STAGE_A(0, 1, t + 2);
    BAR; MMA(0, 1, af0, bf1);
    if (t + 2 < KT) { VMW4; } else { VMW0; }
    BAR;
    LOADA(af0, 0, 1); LOADB(bf0, 0, 1);
    if (t + 2 < KT) { STAGE_A(0, 0, t + 2); STAGE_B(0, 1, t + 2); }
    BAR; MMA(0, 0, af0, bf0); BAR;
    LOADA(af1, 1, 1);
    BAR; MMA(1, 0, af1, bf0); BAR;
    LOADB(bf1, 1, 1);
    if (t + 3 < KT) STAGE_B(1, 0, t + 3);
    BAR; MMA(1, 1, af1, bf1); BAR;
    if (t + 3 < KT) STAGE_A(1, 1, t + 3);
    BAR; MMA(0, 1, af0, bf1);
    if (t + 3 < KT) { VMW4; } else { VMW0; }
    BAR;
  }
  if (KT & 1) {
    LOADA(af0, 0, 0); LOADB(bf0, 0, 0);
    MMA(0, 0, af0, bf0);
    LOADA(af1, 1, 0);
    MMA(1, 0, af1, bf0);
    LOADB(bf1, 1, 0);
    MMA(1, 1, af1, bf1);
    MMA(0, 1, af0, bf1);
  }
#undef STAGE_A
#undef STAGE_B
#undef LOADA
#undef LOADB
#undef MMA

  #pragma unroll
  for (int b = 0; b < 2; ++b)
    #pragma unroll
    for (int nf = 0; nf < 2; ++nf) {
      const int col = bn * 256 + b * 128 + wn * 32 + nf * 16 + l15;
      const float bs = bias[col];
      #pragma unroll
      for (int a = 0; a < 2; ++a)
        #pragma unroll
        for (int mf = 0; mf < 4; ++mf) {
          const int row0 = bm * 256 + a * 128 + wm * 64 + mf * 16 + lq * 4;
          #pragma unroll
          for (int r = 0; r < 4; ++r) {
            float v = acc[a][mf][b][nf][r] + bs;
            if (OUTF32) ((float*)Cout)[(size_t)(row0 + r) * ldc + col] = v;
            else        ((__bf16*)Cout)[(size_t)(row0 + r) * ldc + col] = (__bf16)v;
          }
        }
    }
}

// ---------------- grad combo: inner_grad (blocks 0..767) + dwc_grad (768..959) -----
__global__ __launch_bounds__(256, 3) void grad_combo(
    const __bf16* __restrict__ qkv, const float* __restrict__ w1,
    const float* __restrict__ w2, float* __restrict__ gpart,
    float* __restrict__ w3p)
{
  __shared__ union U {
    struct { __bf16 w1T[64 * LDW], w2T[64 * LDW], kNt1[64 * LDW],
                    kT[64 * LDW], t2T[64 * LDW]; } ig;
    struct { __bf16 kS[6 * 50 * 64]; float red[4][9][64]; } dg;
  } u;
  const int tid = threadIdx.x;

  if (blockIdx.x < 768) {
    const int blk = blockIdx.x;
    const int bh = blk >> 2, seg = blk & 3;
    const int b = bh / H_, h = bh - b * H_;
    const int wid = tid >> 6, lane = tid & 63;
    const int wr = wid >> 1, wc = wid & 1, l15 = lane & 15, lq = lane >> 4;

    const float4* w1p4 = (const float4*)(w1 + h * 4096);
    const float4* w2p4 = (const float4*)(w2 + h * 4096);
    #pragma unroll
    for (int it = 0; it < 4; ++it) {
      int i4 = tid + it * 256;               // float4 index [0,1024)
      float4 a = w1p4[i4], c = w2p4[i4];
      int d = i4 >> 4, e0 = (i4 * 4) & 63;
      u.ig.w1T[(e0+0)*LDW+d] = (__bf16)a.x; u.ig.w1T[(e0+1)*LDW+d] = (__bf16)a.y;
      u.ig.w1T[(e0+2)*LDW+d] = (__bf16)a.z; u.ig.w1T[(e0+3)*LDW+d] = (__bf16)a.w;
      u.ig.w2T[(e0+0)*LDW+d] = (__bf16)c.x; u.ig.w2T[(e0+1)*LDW+d] = (__bf16)c.y;
      u.ig.w2T[(e0+2)*LDW+d] = (__bf16)c.z; u.ig.w2T[(e0+3)*LDW+d] = (__bf16)c.w;
    }

    f32x4 g1a[2][2], g2a[2][2];
    #pragma unroll
    for (int i = 0; i < 2; ++i)
      #pragma unroll
      for (int j = 0; j < 2; ++j) { g1a[i][j] = (f32x4){0.f,0.f,0.f,0.f}; g2a[i][j] = (f32x4){0.f,0.f,0.f,0.f}; }

    const size_t rowb = (size_t)b * N_;
    const int koff = C_ + h * D_;
    const int voff = 2 * C_ + h * D_;
    const int sn = tid >> 2, sdb = tid & 3;
    __syncthreads();

    for (int ci = 0; ci < 9; ++ci) {
      const int n0 = seg * 576 + ci * 64;
      {
        const __bf16* src = qkv + (rowb + n0 + sn) * (size_t)NPAD + koff + sdb * 16;
        bf16x8 va = *(const bf16x8*)src;
        bf16x8 vb = *(const bf16x8*)(src + 8);
        __bf16* kn = &u.ig.kNt1[sn * LDW + sdb * 16];
        *(bf16x4*)(kn + 0)  = __builtin_shufflevector(va, va, 0,1,2,3);
        *(bf16x4*)(kn + 4)  = __builtin_shufflevector(va, va, 4,5,6,7);
        *(bf16x4*)(kn + 8)  = __builtin_shufflevector(vb, vb, 0,1,2,3);
        *(bf16x4*)(kn + 12) = __builtin_shufflevector(vb, vb, 4,5,6,7);
        #pragma unroll
        for (int j = 0; j < 8; ++j) u.ig.kT[(sdb * 16 + j) * LDW + sn] = va[j];
        #pragma unroll
        for (int j = 0; j < 8; ++j) u.ig.kT[(sdb * 16 + 8 + j) * LDW + sn] = vb[j];
      }

      float vv[2][2][4];
      #pragma unroll
      for (int mi = 0; mi < 2; ++mi)
        #pragma unroll
        for (int ni = 0; ni < 2; ++ni) {
          int nl = wr * 32 + mi * 16 + lq * 4;
          int e  = wc * 32 + ni * 16 + l15;
          const __bf16* vp = qkv + (rowb + n0 + nl) * (size_t)NPAD + voff + e;
          #pragma unroll
          for (int r = 0; r < 4; ++r) vv[mi][ni][r] = (float)vp[(size_t)r * NPAD];
        }
      __syncthreads();

      f32x4 z1[2][2], z2[2][2];
      #pragma unroll
      for (int i = 0; i < 2; ++i)
        #pragma unroll
        for (int j = 0; j < 2; ++j) { z1[i][j] = (f32x4){0.f,0.f,0.f,0.f}; z2[i][j] = (f32x4){0.f,0.f,0.f,0.f}; }
      #pragma unroll
      for (int kk = 0; kk < 2; ++kk) {
        bf16x8 af[2], b1[2], b2[2];
        #pragma unroll
        for (int mi = 0; mi < 2; ++mi)
          af[mi] = ld8(&u.ig.kNt1[(wr * 32 + mi * 16 + l15) * LDW + kk * 32 + lq * 8]);
        #pragma unroll
        for (int ni = 0; ni < 2; ++ni) {
          int e = wc * 32 + ni * 16 + l15;
          b1[ni] = ld8(&u.ig.w1T[e * LDW + kk * 32 + lq * 8]);
          b2[ni] = ld8(&u.ig.w2T[e * LDW + kk * 32 + lq * 8]);
        }
        #pragma unroll
        for (int mi = 0; mi < 2; ++mi)
          #pragma unroll
          for (int ni = 0; ni < 2; ++ni) {
            z1[mi][ni] = __builtin_amdgcn_mfma_f32_16x16x32_bf16(af[mi], b1[ni], z1[mi][ni], 0, 0, 0);
            z2[mi][ni] = __builtin_amdgcn_mfma_f32_16x16x32_bf16(af[mi], b2[ni], z2[mi][ni], 0, 0, 0);
          }
      }
      __syncthreads();

      #pragma unroll
      for (int mi = 0; mi < 2; ++mi)
        #pragma unroll
        for (int ni = 0; ni < 2; ++ni) {
          int nl = wr * 32 + mi * 16 + lq * 4;
          int e  = wc * 32 + ni * 16 + l15;
          #pragma unroll
          for (int r = 0; r < 4; ++r) {
            float ev  = vv[mi][ni][r] * EVS;
            float z1v = z1[mi][ni][r], z2v = z2[mi][ni][r];
            float sg  = 1.0f / (1.0f + __expf(-z2v));
            float t1  = ev * (z2v * sg);
            float t2  = ev * z1v * (sg * (1.0f + z2v * (1.0f - sg)));
            u.ig.kNt1[e * LDW + nl + r] = (__bf16)t1;
            u.ig.t2T [e * LDW + nl + r] = (__bf16)t2;
          }
        }
      __syncthreads();

      #pragma unroll
      for (int kk = 0; kk < 2; ++kk) {
        bf16x8 af[2], b1[2], b2[2];
        #pragma unroll
        for (int mi = 0; mi < 2; ++mi)
          af[mi] = ld8(&u.ig.kT[(wr * 32 + mi * 16 + l15) * LDW + kk * 32 + lq * 8]);
        #pragma unroll
        for (int ni = 0; ni < 2; ++ni) {
          int e = wc * 32 + ni * 16 + l15;
          b1[ni] = ld8(&u.ig.kNt1[e * LDW + kk * 32 + lq * 8]);
          b2[ni] = ld8(&u.ig.t2T [e * LDW + kk * 32 + lq * 8]);
        }
        #pragma unroll
        for (int mi = 0; mi < 2; ++mi)
          #pragma unroll
          for (int ni = 0; ni < 2; ++ni) {
            g1a[mi][ni] = __builtin_amdgcn_mfma_f32_16x16x32_bf16(af[mi], b1[ni], g1a[mi][ni], 0, 0, 0);
            g2a[mi][ni] = __builtin_amdgcn_mfma_f32_16x16x32_bf16(af[mi], b2[ni], g2a[mi][ni], 0, 0, 0);
          }
      }
      __syncthreads();
    }

    float* gp = gpart + (size_t)blk * 8192;
    #pragma unroll
    for (int mi = 0; mi < 2; ++mi)
      #pragma unroll
      for (int ni = 0; ni < 2; ++ni)
        #pragma unroll
        for (int r = 0; r < 4; ++r) {
          int d = wr * 32 + mi * 16 + lq * 4 + r;
          int e = wc * 32 + ni * 16 + l15;
          gp[d * 64 + e]        = g1a[mi][ni][r];
          gp[4096 + d * 64 + e] = g2a[mi][ni][r];
        }
  } else {
    const int blk = blockIdx.x - 768;     // 16*12
    const int b = blk / 12, sp = blk - b * 12;
    const int dd = tid & 63, rl = tid >> 6;
    for (int i = tid; i < 9600; i += 256) ((unsigned*)u.dg.kS)[i] = 0u;
    __syncthreads();
    const size_t base = (size_t)b * N_ * NPAD;
    for (int i = tid; i < 6 * 48 * 8; i += 256) {
      int y6 = i / 384; int rem = i - y6 * 384; int x = rem >> 3; int c8 = rem & 7;
      int y = 4 * sp - 1 + y6;
      if (y >= 0 && y < 48) {
        int p = y * 48 + x;
        bf16x8 v = *(const bf16x8*)&qkv[base + (size_t)p * NPAD + 2368 + c8 * 8];
        *(bf16x8*)&u.dg.kS[((y6 * 50) + x + 1) * 64 + c8 * 8] = v;
      }
    }
    __syncthreads();
    float acc[9];
    #pragma unroll
    for (int j = 0; j < 9; ++j) acc[j] = 0.f;
    const int y = 4 * sp + rl;
    for (int x = 0; x < 48; ++x) {
      int p = y * 48 + x;
      float e = (float)qkv[base + (size_t)p * NPAD + 2432 + dd] * EVS;
      #pragma unroll
      for (int j = 0; j < 9; ++j) {
        int ys = j / 3, xs = j - ys * 3;
        acc[j] += (float)u.dg.kS[((rl + ys) * 50 + x + xs) * 64 + dd] * e;
      }
    }
    #pragma unroll
    for (int j = 0; j < 9; ++j) u.dg.red[rl][j][dd] = acc[j];
    __syncthreads();
    if (rl == 0) {
      #pragma unroll
      for (int j = 0; j < 9; ++j) {
        float s = u.dg.red[0][j][dd] + u.dg.red[1][j][dd]
                + u.dg.red[2][j][dd] + u.dg.red[3][j][dd];
        w3p[((size_t)(b * 12 + sp) * 64 + dd) * 9 + j] = s;
      }
    }
  }
}

__global__ __launch_bounds__(256) void inner_upd(
    const float* __restrict__ gpart, const float* __restrict__ w1,
    const float* __restrict__ w2, __bf16* __restrict__ wu)
{
  const int bh = blockIdx.x;
  const int h = bh % H_;
  const int tid = threadIdx.x;
  __shared__ float g1[64 * 65], g2[64 * 65];
  __shared__ float nrm1[64], nrm2[64];
  const float* w1p = w1 + h * 4096;
  const float* w2p = w2 + h * 4096;

  for (int idx = tid; idx < 4096; idx += 256) {
    float s1 = 0.f, s2 = 0.f;
    #pragma unroll
    for (int s = 0; s < 4; ++s) {
      const float* gp = gpart + (size_t)(bh * 4 + s) * 8192;
      s1 += gp[idx]; s2 += gp[4096 + idx];
    }
    int d = idx >> 6, e = idx & 63;
    g1[d * 65 + e] = s1; g2[d * 65 + e] = s2;
  }
  __syncthreads();
  if (tid < 128) {
    const float* gs = (tid < 64) ? g1 : g2;
    int e = tid & 63;
    float s = 0.f;
    for (int d = 0; d < 64; ++d) { float gv = gs[d * 65 + e]; s += gv * gv; }
    float rn = 1.0f / (sqrtf(s) + 1.0f);
    if (tid < 64) nrm1[e] = rn; else nrm2[e] = rn;
  }
  __syncthreads();
  __bf16* wub = wu + (size_t)bh * 8192;
  for (int idx = tid; idx < 4096; idx += 256) {
    int d = idx >> 6, e = idx & 63;
    wub[idx]        = (__bf16)(w1p[idx] - g1[d * 65 + e] * nrm1[e]);
    wub[4096 + idx] = (__bf16)(w2p[idx] - g2[d * 65 + e] * nrm2[e]);
  }
}

// ---------------- apply combo: dwc_apply (blocks 0..191) + inner_apply (192..1343) --
__global__ __launch_bounds__(256) void apply_combo(
    const __bf16* __restrict__ qkv, const __bf16* __restrict__ wu,
    const float* __restrict__ w3p, const float* __restrict__ w3,
    __bf16* __restrict__ concat)
{
  __shared__ union U {
    struct { __bf16 w1T[64 * LDW], w2T[64 * LDW], qN[64 * LDW]; } ia;
    struct { __bf16 qS[6 * 50 * 64]; } da;
  } u;
  const int tid = threadIdx.x;

  if (blockIdx.x >= 192) {
    const int blk = blockIdx.x - 192;
    const int bh = blk / 6, seg = blk - bh * 6;
    const int b = bh / H_, h = bh - b * H_;
    const int wid = tid >> 6, lane = tid & 63;
    const int wr = wid >> 1, wc = wid & 1, l15 = lane & 15, lq = lane >> 4;

    const bf16x8* wub8 = (const bf16x8*)(wu + (size_t)bh * 8192);
    #pragma unroll
    for (int it = 0; it < 2; ++it) {
      int i8 = tid + it * 256;               // bf16x8 index [0,512)
      bf16x8 a = wub8[i8], c = wub8[512 + i8];
      int d = i8 >> 3, e0 = (i8 & 7) * 8;
      #pragma unroll
      for (int j = 0; j < 8; ++j) {
        u.ia.w1T[(e0+j)*LDW+d] = a[j];
        u.ia.w2T[(e0+j)*LDW+d] = c[j];
      }
    }

    const size_t rowb = (size_t)b * N_;
    const int qoff = h * D_;
    const int sn = tid >> 2, sdb = tid & 3;

    for (int ci = 0; ci < 6; ++ci) {
      const int n0 = seg * 384 + ci * 64;
      {
        const __bf16* src = qkv + (rowb + n0 + sn) * (size_t)NPAD + qoff + sdb * 16;
        bf16x8 va = *(const bf16x8*)src;
        bf16x8 vb = *(const bf16x8*)(src + 8);
        __bf16* kn = &u.ia.qN[sn * LDW + sdb * 16];
        *(bf16x4*)(kn + 0)  = __builtin_shufflevector(va, va, 0,1,2,3);
        *(bf16x4*)(kn + 4)  = __builtin_shufflevector(va, va, 4,5,6,7);
        *(bf16x4*)(kn + 8)  = __builtin_shufflevector(vb, vb, 0,1,2,3);
        *(bf16x4*)(kn + 12) = __builtin_shufflevector(vb, vb, 4,5,6,7);
      }
      __syncthreads();
      f32x4 y1[2][2], y2[2][2];
      #pragma unroll
      for (int i = 0; i < 2; ++i)
        #pragma unroll
        for (int j = 0; j < 2; ++j) { y1[i][j] = (f32x4){0.f,0.f,0.f,0.f}; y2[i][j] = (f32x4){0.f,0.f,0.f,0.f}; }
      #pragma unroll
      for (int kk = 0; kk < 2; ++kk) {
        bf16x8 af[2], b1[2], b2[2];
        #pragma unroll
        for (int mi = 0; mi < 2; ++mi)
          af[mi] = ld8(&u.ia.qN[(wr * 32 + mi * 16 + l15) * LDW + kk * 32 + lq * 8]);
        #pragma unroll
        for (int ni = 0; ni < 2; ++ni) {
          int e = wc * 32 + ni * 16 + l15;
          b1[ni] = ld8(&u.ia.w1T[e * LDW + kk * 32 + lq * 8]);
          b2[ni] = ld8(&u.ia.w2T[e * LDW + kk * 32 + lq * 8]);
        }
        #pragma unroll
        for (int mi = 0; mi < 2; ++mi)
          #pragma unroll
          for (int ni = 0; ni < 2; ++ni) {
            y1[mi][ni] = __builtin_amdgcn_mfma_f32_16x16x32_bf16(af[mi], b1[ni], y1[mi][ni], 0, 0, 0);
            y2[mi][ni] = __builtin_amdgcn_mfma_f32_16x16x32_bf16(af[mi], b2[ni], y2[mi][ni], 0, 0, 0);
          }
      }
      #pragma unroll
      for (int mi = 0; mi < 2; ++mi)
        #pragma unroll
        for (int ni = 0; ni < 2; ++ni) {
          int nl = wr * 32 + mi * 16 + lq * 4;
          int e  = wc * 32 + ni * 16 + l15;
          #pragma unroll
          for (int r = 0; r < 4; ++r) {
            float a1 = y1[mi][ni][r], a2 = y2[mi][ni][r];
            float sg = 1.0f / (1.0f + __expf(-a2));
            concat[(rowb + n0 + nl + r) * (size_t)CCP + h * D_ + e] = (__bf16)(a1 * (a2 * sg));
          }
        }
      __syncthreads();
    }
  } else {
    const int blk = blockIdx.x;
    const int b = blk / 12, sp = blk - b * 12;
    const int dd = tid & 63, rl = tid >> 6;
    for (int i = tid; i < 9600; i += 256) ((unsigned*)u.da.qS)[i] = 0u;
    __syncthreads();
    const size_t base = (size_t)b * N_ * NPAD;
    for (int i = tid; i < 6 * 48 * 8; i += 256) {
      int y6 = i / 384; int rem = i - y6 * 384; int x = rem >> 3; int c8 = rem & 7;
      int y = 4 * sp - 1 + y6;
      if (y >= 0 && y < 48) {
        int p = y * 48 + x;
        bf16x8 v = *(const bf16x8*)&qkv[base + (size_t)p * NPAD + 2304 + c8 * 8];
        *(bf16x8*)&u.da.qS[((y6 * 50) + x + 1) * 64 + c8 * 8] = v;
      }
    }
    float g[9];
    #pragma unroll
    for (int j = 0; j < 9; ++j) g[j] = 0.f;
    for (int s = 0; s < 12; ++s)
      #pragma unroll
      for (int j = 0; j < 9; ++j)
        g[j] += w3p[((size_t)(b * 12 + s) * 64 + dd) * 9 + j];
    float ss = 0.f;
    #pragma unroll
    for (int j = 0; j < 9; ++j) ss += g[j] * g[j];
    float rn = 1.0f / (sqrtf(ss) + 1.0f);
    float wv[9];
    #pragma unroll
    for (int j = 0; j < 9; ++j) wv[j] = w3[dd * 9 + j] - g[j] * rn;
    __syncthreads();
    const int y = 4 * sp + rl;
    for (int x = 0; x < 48; ++x) {
      float s = 0.f;
      #pragma unroll
      for (int j = 0; j < 9; ++j) {
        int ys = j / 3, xs = j - ys * 3;
        s += (float)u.da.qS[((rl + ys) * 50 + x + xs) * 64 + dd] * wv[j];
      }
      int p = y * 48 + x;
      concat[((size_t)b * N_ + p) * CCP + 768 + dd] = (__bf16)s;
    }
  }
}

// ---------------- launcher ----------------
extern "C" void kernel_launch(void* const* d_in, const int* in_sizes, int n_in,
                              void* d_out, int out_size, void* d_ws, size_t ws_size,
                              hipStream_t stream) {
  const float* x      = (const float*)d_in[0];
  const float* qkv_w  = (const float*)d_in[1];
  const float* qkv_b  = (const float*)d_in[2];
  const float* w1     = (const float*)d_in[3];
  const float* w2     = (const float*)d_in[4];
  const float* w3     = (const float*)d_in[5];
  const float* proj_w = (const float*)d_in[6];
  const float* proj_b = (const float*)d_in[7];

  char* ws = (char*)d_ws;
  __bf16* wqkvb  = (__bf16*)(ws + 56623104);        //  3,932,160 B
  float*  qkvbp  = (float*) (ws + 60555264);        //     10,240 B
  __bf16* concat = (__bf16*)ws;                     // 61,341,696 B (stride 832)
  __bf16* qkvb16 = (__bf16*)(ws + 66060288);        // 188,743,680 B
  __bf16* pwb    = (__bf16*)(ws + 254803968);       //  1,277,952 B
  float*  w3p    = (float*) (ws + 256217088);       //    442,368 B
  float*  gpart  = (float*) (ws + 256659456);       // 25,165,824 B
  __bf16* wu     = (__bf16*)(ws + 281825280);       //  3,145,728 B

  cvt_all<<<1272, 256, 0, stream>>>(qkv_w, qkv_b, proj_w, wqkvb, qkvbp, pwb);

  // QKV GEMM (fused f32->bf16 A): [36864 x 768]f32 @ [768 x 2560] -> grid 1440
  gemmXF<<<1440, 512, 0, stream>>>(x, wqkvb, qkvbp, qkvb16,
                                   768, NPAD, 10, 12);

  grad_combo <<< 960, 256, 0, stream>>>(qkvb16, w1, w2, gpart, w3p);
  inner_upd  <<< 192, 256, 0, stream>>>(gpart, w1, w2, wu);
  apply_combo<<<1344, 256, 0, stream>>>(qkvb16, wu, w3p, w3, concat);

  // proj GEMM: [36864 x 832] @ [832 x 768] -> grid 144*3 = 432, KT=13
  gemm8<1><<<432, 512, 0, stream>>>(concat, pwb, proj_b, d_out,
                                    832, 768, 3, 13);
}

// Round 16
// 393.846 us; speedup vs baseline: 1.0657x; 1.0657x over previous
//
#include <hip/hip_runtime.h>
#include <hip/hip_bf16.h>
#include <math.h>

#define B_   16
#define N_   2304
#define C_   768
#define H_   12
#define D_   64
#define M_   (B_*N_)      // 36864
#define NQKV 2496
#define NPAD 2560
#define CCP  832          // concat stride = 13 K-tiles of 64, exact
#define LDW  76           // inner-kernel LDS row stride: 152B = 38 dwords -> bank
                          // stride 6 (gcd 2 with 32): 16-lane scatter = conflict-free,
                          // and 152%8==0 keeps ds_read_b64 alignment
#define EVS  (-1.0f/6912.0f)   // -SCALE/N = -(1/3)/2304

typedef __bf16 bf16x8 __attribute__((ext_vector_type(8)));
typedef __bf16 bf16x4 __attribute__((ext_vector_type(4)));
typedef float  f32x4  __attribute__((ext_vector_type(4)));

static __device__ __forceinline__ void gload_lds16(const void* g, void* l) {
  __builtin_amdgcn_global_load_lds((const __attribute__((address_space(1))) void*)g,
                                   (__attribute__((address_space(3))) void*)l, 16, 0, 0);
}

static __device__ __forceinline__ bf16x8 ld8(const __bf16* p) {
  bf16x4 lo = *(const bf16x4*)p;
  bf16x4 hi = *(const bf16x4*)(p + 4);
  return __builtin_shufflevector(lo, hi, 0,1,2,3,4,5,6,7);
}

// ---------------- fused converts (1 launch) ----------------
__global__ __launch_bounds__(256) void cvt_all(
    const float* __restrict__ x, const float* __restrict__ qkv_w,
    const float* __restrict__ qkv_b, const float* __restrict__ proj_w,
    __bf16* __restrict__ xb, __bf16* __restrict__ wqkvb,
    float* __restrict__ qkvbp, __bf16* __restrict__ pwb)
{
  const int blk = blockIdx.x;
  if (blk < 13824) {
    int i = blk * 256 + threadIdx.x;
    const float4* p = (const float4*)(x + (size_t)i * 8);
    float4 a = p[0], b = p[1];
    bf16x8 o = {(__bf16)a.x,(__bf16)a.y,(__bf16)a.z,(__bf16)a.w,
                (__bf16)b.x,(__bf16)b.y,(__bf16)b.z,(__bf16)b.w};
    *(bf16x8*)(xb + (size_t)i * 8) = o;
  } else if (blk < 14784) {
    int i = (blk - 13824) * 256 + threadIdx.x;   // [0, 245760)
    int n = i / 96, c8 = i - n * 96;
    bf16x8 o;
    if (n < NQKV) {
      const float4* p = (const float4*)(qkv_w + (size_t)n * 768 + c8 * 8);
      float4 a = p[0], b = p[1];
      o = (bf16x8){(__bf16)a.x,(__bf16)a.y,(__bf16)a.z,(__bf16)a.w,
                   (__bf16)b.x,(__bf16)b.y,(__bf16)b.z,(__bf16)b.w};
    } else {
      o = (bf16x8){(__bf16)0.f,(__bf16)0.f,(__bf16)0.f,(__bf16)0.f,
                   (__bf16)0.f,(__bf16)0.f,(__bf16)0.f,(__bf16)0.f};
    }
    *(bf16x8*)(wqkvb + (size_t)n * 768 + c8 * 8) = o;
    if (i < NPAD) qkvbp[i] = (i < NQKV) ? qkv_b[i] : 0.0f;
  } else {
    int i = (blk - 14784) * 256 + threadIdx.x;   // [0, 79872)
    if (i >= 79872) return;
    const float4* p = (const float4*)(proj_w + (size_t)i * 8);
    float4 a = p[0], b = p[1];
    bf16x8 o = {(__bf16)a.x,(__bf16)a.y,(__bf16)a.z,(__bf16)a.w,
                (__bf16)b.x,(__bf16)b.y,(__bf16)b.z,(__bf16)b.w};
    *(bf16x8*)(pwb + (size_t)i * 8) = o;
  }
}

// ---------------- GEMM: 256x256, BK=64, 8-phase dbuf (frozen; best measured) --------
template<int OUTF32>
__global__ __launch_bounds__(512, 2) void gemm8(
    const __bf16* __restrict__ A, const __bf16* __restrict__ Bt,
    const float* __restrict__ bias, void* __restrict__ Cout,
    const int K, const int ldc, const int nbn, const int KT)
{
  __shared__ __align__(16) __bf16 sA[2][2][128 * 64];
  __shared__ __align__(16) __bf16 sB[2][2][128 * 64];
  const int tid  = threadIdx.x;
  const int lane = tid & 63;
  const int wid  = tid >> 6;
  const int wm = wid >> 2;       // 0..1
  const int wn = wid & 3;        // 0..3
  const int l15 = lane & 15, lq = lane >> 4;

  const int nwg = gridDim.x;
  const int swz = ((int)blockIdx.x & 7) * (nwg >> 3) + ((int)blockIdx.x >> 3);
  const int bm = swz / nbn;
  const int bn = swz - bm * nbn;

  const int strow = tid >> 3;                       // 0..63
  const int stoff = strow * 64 + (tid & 7) * 8;     // linear LDS dest (elements)
  const __bf16* gA = A  + (size_t)((size_t)bm * 256 + strow) * K + ((tid & 7) ^ (strow & 7)) * 8;
  const __bf16* gB = Bt + (size_t)((size_t)bn * 256 + strow) * K + ((tid & 7) ^ (strow & 7)) * 8;

  f32x4 acc[2][4][2][2];
  #pragma unroll
  for (int a = 0; a < 2; ++a)
    #pragma unroll
    for (int m = 0; m < 4; ++m)
      #pragma unroll
      for (int b = 0; b < 2; ++b)
        #pragma unroll
        for (int n = 0; n < 2; ++n) acc[a][m][b][n] = (f32x4){0.f,0.f,0.f,0.f};

  bf16x8 af0[4][2], af1[4][2], bf0[2][2], bf1[2][2];

#define STAGE_A(q, h, T) do {                                                   \
    const size_t ko_ = (size_t)(T) * 64;                                        \
    gload_lds16(gA + (size_t)((h)*128 +  0) * K + ko_, &sA[q][h][stoff]);       \
    gload_lds16(gA + (size_t)((h)*128 + 64) * K + ko_, &sA[q][h][4096 + stoff]);\
  } while (0)
#define STAGE_B(q, h, T) do {                                                   \
    const size_t ko_ = (size_t)(T) * 64;                                        \
    gload_lds16(gB + (size_t)((h)*128 +  0) * K + ko_, &sB[q][h][stoff]);       \
    gload_lds16(gB + (size_t)((h)*128 + 64) * K + ko_, &sB[q][h][4096 + stoff]);\
  } while (0)
#define LOADA(DST, h, q) do {                                                   \
    _Pragma("unroll") for (int mf_ = 0; mf_ < 4; ++mf_) {                       \
      const int r_ = wm * 64 + mf_ * 16 + l15;                                  \
      _Pragma("unroll") for (int kk_ = 0; kk_ < 2; ++kk_)                       \
        DST[mf_][kk_] = *(const bf16x8*)&sA[q][h][r_ * 64 + (((kk_*4+lq) ^ (r_&7)) * 8)]; \
    } } while (0)
#define LOADB(DST, h, q) do {                                                   \
    _Pragma("unroll") for (int nf_ = 0; nf_ < 2; ++nf_) {                       \
      const int c_ = wn * 32 + nf_ * 16 + l15;                                  \
      _Pragma("unroll") for (int kk_ = 0; kk_ < 2; ++kk_)                       \
        DST[nf_][kk_] = *(const bf16x8*)&sB[q][h][c_ * 64 + (((kk_*4+lq) ^ (c_&7)) * 8)]; \
    } } while (0)
#define MMA(a_, b_, AF, BF) do {                                                \
    __builtin_amdgcn_s_setprio(1);                                              \
    _Pragma("unroll") for (int kk_ = 0; kk_ < 2; ++kk_)                         \
    _Pragma("unroll") for (int mf_ = 0; mf_ < 4; ++mf_)                         \
    _Pragma("unroll") for (int nf_ = 0; nf_ < 2; ++nf_)                         \
      acc[a_][mf_][b_][nf_] = __builtin_amdgcn_mfma_f32_16x16x32_bf16(          \
          AF[mf_][kk_], BF[nf_][kk_], acc[a_][mf_][b_][nf_], 0, 0, 0);          \
    __builtin_amdgcn_s_setprio(0);                                              \
  } while (0)
#define BAR  __builtin_amdgcn_s_barrier()
#define VMW4 asm volatile("s_waitcnt vmcnt(4)" ::: "memory")
#define VMW0 asm volatile("s_waitcnt vmcnt(0)" ::: "memory")

  // prologue: tile0 fully (8 loads), then B0(1), A1(1) (4 loads)
  STAGE_A(0, 0, 0); STAGE_A(0, 1, 0); STAGE_B(0, 0, 0); STAGE_B(0, 1, 0);
  STAGE_B(1, 0, 1);
  STAGE_A(1, 1, 1);
  VMW4;   // tile0 landed; B0(1), A1(1) in flight
  BAR;

  for (int t = 0; t + 1 < KT; t += 2) {
    LOADA(af0, 0, 0); LOADB(bf0, 0, 0);
    STAGE_A(1, 0, t + 1); STAGE_B(1, 1, t + 1);
    BAR; MMA(0, 0, af0, bf0); BAR;
    LOADA(af1, 1, 0);
    BAR; MMA(1, 0, af1, bf0); BAR;
    LOADB(bf1, 1, 0);
    if (t + 2 < KT) STAGE_B(0, 0, t + 2);
    BAR; MMA(1, 1, af1, bf1); BAR;
    if (t + 2 < KT) STAGE_A(0, 1, t + 2);
    BAR; MMA(0, 1, af0, bf1);
    if (t + 2 < KT) { VMW4; } else { VMW0; }
    BAR;
    LOADA(af0, 0, 1); LOADB(bf0, 0, 1);
    if (t + 2 < KT) { STAGE_A(0, 0, t + 2); STAGE_B(0, 1, t + 2); }
    BAR; MMA(0, 0, af0, bf0); BAR;
    LOADA(af1, 1, 1);
    BAR; MMA(1, 0, af1, bf0); BAR;
    LOADB(bf1, 1, 1);
    if (t + 3 < KT) STAGE_B(1, 0, t + 3);
    BAR; MMA(1, 1, af1, bf1); BAR;
    if (t + 3 < KT) STAGE_A(1, 1, t + 3);
    BAR; MMA(0, 1, af0, bf1);
    if (t + 3 < KT) { VMW4; } else { VMW0; }
    BAR;
  }
  if (KT & 1) {
    LOADA(af0, 0, 0); LOADB(bf0, 0, 0);
    MMA(0, 0, af0, bf0);
    LOADA(af1, 1, 0);
    MMA(1, 0, af1, bf0);
    LOADB(bf1, 1, 0);
    MMA(1, 1, af1, bf1);
    MMA(0, 1, af0, bf1);
  }
#undef STAGE_A
#undef STAGE_B
#undef LOADA
#undef LOADB
#undef MMA

  #pragma unroll
  for (int b = 0; b < 2; ++b)
    #pragma unroll
    for (int nf = 0; nf < 2; ++nf) {
      const int col = bn * 256 + b * 128 + wn * 32 + nf * 16 + l15;
      const float bs = bias[col];
      #pragma unroll
      for (int a = 0; a < 2; ++a)
        #pragma unroll
        for (int mf = 0; mf < 4; ++mf) {
          const int row0 = bm * 256 + a * 128 + wm * 64 + mf * 16 + lq * 4;
          #pragma unroll
          for (int r = 0; r < 4; ++r) {
            float v = acc[a][mf][b][nf][r] + bs;
            if (OUTF32) ((float*)Cout)[(size_t)(row0 + r) * ldc + col] = v;
            else        ((__bf16*)Cout)[(size_t)(row0 + r) * ldc + col] = (__bf16)v;
          }
        }
    }
}

// ---------------- grad combo: inner_grad (blocks 0..767) + dwc_grad (768..959) -----
__global__ __launch_bounds__(256, 3) void grad_combo(
    const __bf16* __restrict__ qkv, const float* __restrict__ w1,
    const float* __restrict__ w2, float* __restrict__ gpart,
    float* __restrict__ w3p)
{
  __shared__ union U {
    struct { __bf16 w1T[64 * LDW], w2T[64 * LDW], kNt1[64 * LDW],
                    kT[64 * LDW], t2T[64 * LDW]; } ig;
    struct { __bf16 kS[6 * 50 * 64]; float red[4][9][64]; } dg;
  } u;
  const int tid = threadIdx.x;

  if (blockIdx.x < 768) {
    const int blk = blockIdx.x;
    const int bh = blk >> 2, seg = blk & 3;
    const int b = bh / H_, h = bh - b * H_;
    const int wid = tid >> 6, lane = tid & 63;
    const int wr = wid >> 1, wc = wid & 1, l15 = lane & 15, lq = lane >> 4;

    const float4* w1p4 = (const float4*)(w1 + h * 4096);
    const float4* w2p4 = (const float4*)(w2 + h * 4096);
    #pragma unroll
    for (int it = 0; it < 4; ++it) {
      int i4 = tid + it * 256;               // float4 index [0,1024)
      float4 a = w1p4[i4], c = w2p4[i4];
      int d = i4 >> 4, e0 = (i4 * 4) & 63;
      u.ig.w1T[(e0+0)*LDW+d] = (__bf16)a.x; u.ig.w1T[(e0+1)*LDW+d] = (__bf16)a.y;
      u.ig.w1T[(e0+2)*LDW+d] = (__bf16)a.z; u.ig.w1T[(e0+3)*LDW+d] = (__bf16)a.w;
      u.ig.w2T[(e0+0)*LDW+d] = (__bf16)c.x; u.ig.w2T[(e0+1)*LDW+d] = (__bf16)c.y;
      u.ig.w2T[(e0+2)*LDW+d] = (__bf16)c.z; u.ig.w2T[(e0+3)*LDW+d] = (__bf16)c.w;
    }

    f32x4 g1a[2][2], g2a[2][2];
    #pragma unroll
    for (int i = 0; i < 2; ++i)
      #pragma unroll
      for (int j = 0; j < 2; ++j) { g1a[i][j] = (f32x4){0.f,0.f,0.f,0.f}; g2a[i][j] = (f32x4){0.f,0.f,0.f,0.f}; }

    const size_t rowb = (size_t)b * N_;
    const int koff = C_ + h * D_;
    const int voff = 2 * C_ + h * D_;
    const int sn = tid >> 2, sdb = tid & 3;
    __syncthreads();

    for (int ci = 0; ci < 9; ++ci) {
      const int n0 = seg * 576 + ci * 64;
      {
        const __bf16* src = qkv + (rowb + n0 + sn) * (size_t)NPAD + koff + sdb * 16;
        bf16x8 va = *(const bf16x8*)src;
        bf16x8 vb = *(const bf16x8*)(src + 8);
        __bf16* kn = &u.ig.kNt1[sn * LDW + sdb * 16];
        *(bf16x4*)(kn + 0)  = __builtin_shufflevector(va, va, 0,1,2,3);
        *(bf16x4*)(kn + 4)  = __builtin_shufflevector(va, va, 4,5,6,7);
        *(bf16x4*)(kn + 8)  = __builtin_shufflevector(vb, vb, 0,1,2,3);
        *(bf16x4*)(kn + 12) = __builtin_shufflevector(vb, vb, 4,5,6,7);
        #pragma unroll
        for (int j = 0; j < 8; ++j) u.ig.kT[(sdb * 16 + j) * LDW + sn] = va[j];
        #pragma unroll
        for (int j = 0; j < 8; ++j) u.ig.kT[(sdb * 16 + 8 + j) * LDW + sn] = vb[j];
      }

      // T14 issue-early: prefetch this chunk's v into regs (consumed post-z)
      float vv[2][2][4];
      #pragma unroll
      for (int mi = 0; mi < 2; ++mi)
        #pragma unroll
        for (int ni = 0; ni < 2; ++ni) {
          int nl = wr * 32 + mi * 16 + lq * 4;
          int e  = wc * 32 + ni * 16 + l15;
          const __bf16* vp = qkv + (rowb + n0 + nl) * (size_t)NPAD + voff + e;
          #pragma unroll
          for (int r = 0; r < 4; ++r) vv[mi][ni][r] = (float)vp[(size_t)r * NPAD];
        }
      __syncthreads();

      f32x4 z1[2][2], z2[2][2];
      #pragma unroll
      for (int i = 0; i < 2; ++i)
        #pragma unroll
        for (int j = 0; j < 2; ++j) { z1[i][j] = (f32x4){0.f,0.f,0.f,0.f}; z2[i][j] = (f32x4){0.f,0.f,0.f,0.f}; }
      #pragma unroll
      for (int kk = 0; kk < 2; ++kk) {
        bf16x8 af[2], b1[2], b2[2];
        #pragma unroll
        for (int mi = 0; mi < 2; ++mi)
          af[mi] = ld8(&u.ig.kNt1[(wr * 32 + mi * 16 + l15) * LDW + kk * 32 + lq * 8]);
        #pragma unroll
        for (int ni = 0; ni < 2; ++ni) {
          int e = wc * 32 + ni * 16 + l15;
          b1[ni] = ld8(&u.ig.w1T[e * LDW + kk * 32 + lq * 8]);
          b2[ni] = ld8(&u.ig.w2T[e * LDW + kk * 32 + lq * 8]);
        }
        #pragma unroll
        for (int mi = 0; mi < 2; ++mi)
          #pragma unroll
          for (int ni = 0; ni < 2; ++ni) {
            z1[mi][ni] = __builtin_amdgcn_mfma_f32_16x16x32_bf16(af[mi], b1[ni], z1[mi][ni], 0, 0, 0);
            z2[mi][ni] = __builtin_amdgcn_mfma_f32_16x16x32_bf16(af[mi], b2[ni], z2[mi][ni], 0, 0, 0);
          }
      }
      __syncthreads();

      #pragma unroll
      for (int mi = 0; mi < 2; ++mi)
        #pragma unroll
        for (int ni = 0; ni < 2; ++ni) {
          int nl = wr * 32 + mi * 16 + lq * 4;
          int e  = wc * 32 + ni * 16 + l15;
          #pragma unroll
          for (int r = 0; r < 4; ++r) {
            float ev  = vv[mi][ni][r] * EVS;
            float z1v = z1[mi][ni][r], z2v = z2[mi][ni][r];
            float sg  = 1.0f / (1.0f + __expf(-z2v));
            float t1  = ev * (z2v * sg);
            float t2  = ev * z1v * (sg * (1.0f + z2v * (1.0f - sg)));
            u.ig.kNt1[e * LDW + nl + r] = (__bf16)t1;
            u.ig.t2T [e * LDW + nl + r] = (__bf16)t2;
          }
        }
      __syncthreads();

      #pragma unroll
      for (int kk = 0; kk < 2; ++kk) {
        bf16x8 af[2], b1[2], b2[2];
        #pragma unroll
        for (int mi = 0; mi < 2; ++mi)
          af[mi] = ld8(&u.ig.kT[(wr * 32 + mi * 16 + l15) * LDW + kk * 32 + lq * 8]);
        #pragma unroll
        for (int ni = 0; ni < 2; ++ni) {
          int e = wc * 32 + ni * 16 + l15;
          b1[ni] = ld8(&u.ig.kNt1[e * LDW + kk * 32 + lq * 8]);
          b2[ni] = ld8(&u.ig.t2T [e * LDW + kk * 32 + lq * 8]);
        }
        #pragma unroll
        for (int mi = 0; mi < 2; ++mi)
          #pragma unroll
          for (int ni = 0; ni < 2; ++ni) {
            g1a[mi][ni] = __builtin_amdgcn_mfma_f32_16x16x32_bf16(af[mi], b1[ni], g1a[mi][ni], 0, 0, 0);
            g2a[mi][ni] = __builtin_amdgcn_mfma_f32_16x16x32_bf16(af[mi], b2[ni], g2a[mi][ni], 0, 0, 0);
          }
      }
      __syncthreads();
    }

    float* gp = gpart + (size_t)blk * 8192;
    #pragma unroll
    for (int mi = 0; mi < 2; ++mi)
      #pragma unroll
      for (int ni = 0; ni < 2; ++ni)
        #pragma unroll
        for (int r = 0; r < 4; ++r) {
          int d = wr * 32 + mi * 16 + lq * 4 + r;
          int e = wc * 32 + ni * 16 + l15;
          gp[d * 64 + e]        = g1a[mi][ni][r];
          gp[4096 + d * 64 + e] = g2a[mi][ni][r];
        }
  } else {
    // ---------- dwc_grad ----------
    const int blk = blockIdx.x - 768;     // 16*12
    const int b = blk / 12, sp = blk - b * 12;
    const int dd = tid & 63, rl = tid >> 6;
    for (int i = tid; i < 9600; i += 256) ((unsigned*)u.dg.kS)[i] = 0u;
    __syncthreads();
    const size_t base = (size_t)b * N_ * NPAD;
    for (int i = tid; i < 6 * 48 * 8; i += 256) {
      int y6 = i / 384; int rem = i - y6 * 384; int x = rem >> 3; int c8 = rem & 7;
      int y = 4 * sp - 1 + y6;
      if (y >= 0 && y < 48) {
        int p = y * 48 + x;
        bf16x8 v = *(const bf16x8*)&qkv[base + (size_t)p * NPAD + 2368 + c8 * 8];
        *(bf16x8*)&u.dg.kS[((y6 * 50) + x + 1) * 64 + c8 * 8] = v;
      }
    }
    __syncthreads();
    float acc[9];
    #pragma unroll
    for (int j = 0; j < 9; ++j) acc[j] = 0.f;
    const int y = 4 * sp + rl;
    for (int x = 0; x < 48; ++x) {
      int p = y * 48 + x;
      float e = (float)qkv[base + (size_t)p * NPAD + 2432 + dd] * EVS;
      #pragma unroll
      for (int j = 0; j < 9; ++j) {
        int ys = j / 3, xs = j - ys * 3;
        acc[j] += (float)u.dg.kS[((rl + ys) * 50 + x + xs) * 64 + dd] * e;
      }
    }
    #pragma unroll
    for (int j = 0; j < 9; ++j) u.dg.red[rl][j][dd] = acc[j];
    __syncthreads();
    if (rl == 0) {
      #pragma unroll
      for (int j = 0; j < 9; ++j) {
        float s = u.dg.red[0][j][dd] + u.dg.red[1][j][dd]
                + u.dg.red[2][j][dd] + u.dg.red[3][j][dd];
        w3p[((size_t)(b * 12 + sp) * 64 + dd) * 9 + j] = s;
      }
    }
  }
}

__global__ __launch_bounds__(256) void inner_upd(
    const float* __restrict__ gpart, const float* __restrict__ w1,
    const float* __restrict__ w2, __bf16* __restrict__ wu)
{
  const int bh = blockIdx.x;
  const int h = bh % H_;
  const int tid = threadIdx.x;
  __shared__ float g1[64 * 65], g2[64 * 65];
  __shared__ float nrm1[64], nrm2[64];
  const float* w1p = w1 + h * 4096;
  const float* w2p = w2 + h * 4096;

  for (int idx = tid; idx < 4096; idx += 256) {
    float s1 = 0.f, s2 = 0.f;
    #pragma unroll
    for (int s = 0; s < 4; ++s) {
      const float* gp = gpart + (size_t)(bh * 4 + s) * 8192;
      s1 += gp[idx]; s2 += gp[4096 + idx];
    }
    int d = idx >> 6, e = idx & 63;
    g1[d * 65 + e] = s1; g2[d * 65 + e] = s2;
  }
  __syncthreads();
  if (tid < 128) {
    const float* gs = (tid < 64) ? g1 : g2;
    int e = tid & 63;
    float s = 0.f;
    for (int d = 0; d < 64; ++d) { float gv = gs[d * 65 + e]; s += gv * gv; }
    float rn = 1.0f / (sqrtf(s) + 1.0f);
    if (tid < 64) nrm1[e] = rn; else nrm2[e] = rn;
  }
  __syncthreads();
  __bf16* wub = wu + (size_t)bh * 8192;
  for (int idx = tid; idx < 4096; idx += 256) {
    int d = idx >> 6, e = idx & 63;
    wub[idx]        = (__bf16)(w1p[idx] - g1[d * 65 + e] * nrm1[e]);
    wub[4096 + idx] = (__bf16)(w2p[idx] - g2[d * 65 + e] * nrm2[e]);
  }
}

// ---------------- apply combo: dwc_apply (blocks 0..191) + inner_apply (192..1343) --
__global__ __launch_bounds__(256) void apply_combo(
    const __bf16* __restrict__ qkv, const __bf16* __restrict__ wu,
    const float* __restrict__ w3p, const float* __restrict__ w3,
    __bf16* __restrict__ concat)
{
  __shared__ union U {
    struct { __bf16 w1T[64 * LDW], w2T[64 * LDW], qN[64 * LDW]; } ia;
    struct { __bf16 qS[6 * 50 * 64]; } da;
  } u;
  const int tid = threadIdx.x;

  if (blockIdx.x >= 192) {
    // ---------- inner_apply ----------
    const int blk = blockIdx.x - 192;
    const int bh = blk / 6, seg = blk - bh * 6;
    const int b = bh / H_, h = bh - b * H_;
    const int wid = tid >> 6, lane = tid & 63;
    const int wr = wid >> 1, wc = wid & 1, l15 = lane & 15, lq = lane >> 4;

    const bf16x8* wub8 = (const bf16x8*)(wu + (size_t)bh * 8192);
    #pragma unroll
    for (int it = 0; it < 2; ++it) {
      int i8 = tid + it * 256;               // bf16x8 index [0,512)
      bf16x8 a = wub8[i8], c = wub8[512 + i8];
      int d = i8 >> 3, e0 = (i8 & 7) * 8;
      #pragma unroll
      for (int j = 0; j < 8; ++j) {
        u.ia.w1T[(e0+j)*LDW+d] = a[j];
        u.ia.w2T[(e0+j)*LDW+d] = c[j];
      }
    }

    const size_t rowb = (size_t)b * N_;
    const int qoff = h * D_;
    const int sn = tid >> 2, sdb = tid & 3;

    for (int ci = 0; ci < 6; ++ci) {
      const int n0 = seg * 384 + ci * 64;
      {
        const __bf16* src = qkv + (rowb + n0 + sn) * (size_t)NPAD + qoff + sdb * 16;
        bf16x8 va = *(const bf16x8*)src;
        bf16x8 vb = *(const bf16x8*)(src + 8);
        __bf16* kn = &u.ia.qN[sn * LDW + sdb * 16];
        *(bf16x4*)(kn + 0)  = __builtin_shufflevector(va, va, 0,1,2,3);
        *(bf16x4*)(kn + 4)  = __builtin_shufflevector(va, va, 4,5,6,7);
        *(bf16x4*)(kn + 8)  = __builtin_shufflevector(vb, vb, 0,1,2,3);
        *(bf16x4*)(kn + 12) = __builtin_shufflevector(vb, vb, 4,5,6,7);
      }
      __syncthreads();
      f32x4 y1[2][2], y2[2][2];
      #pragma unroll
      for (int i = 0; i < 2; ++i)
        #pragma unroll
        for (int j = 0; j < 2; ++j) { y1[i][j] = (f32x4){0.f,0.f,0.f,0.f}; y2[i][j] = (f32x4){0.f,0.f,0.f,0.f}; }
      #pragma unroll
      for (int kk = 0; kk < 2; ++kk) {
        bf16x8 af[2], b1[2], b2[2];
        #pragma unroll
        for (int mi = 0; mi < 2; ++mi)
          af[mi] = ld8(&u.ia.qN[(wr * 32 + mi * 16 + l15) * LDW + kk * 32 + lq * 8]);
        #pragma unroll
        for (int ni = 0; ni < 2; ++ni) {
          int e = wc * 32 + ni * 16 + l15;
          b1[ni] = ld8(&u.ia.w1T[e * LDW + kk * 32 + lq * 8]);
          b2[ni] = ld8(&u.ia.w2T[e * LDW + kk * 32 + lq * 8]);
        }
        #pragma unroll
        for (int mi = 0; mi < 2; ++mi)
          #pragma unroll
          for (int ni = 0; ni < 2; ++ni) {
            y1[mi][ni] = __builtin_amdgcn_mfma_f32_16x16x32_bf16(af[mi], b1[ni], y1[mi][ni], 0, 0, 0);
            y2[mi][ni] = __builtin_amdgcn_mfma_f32_16x16x32_bf16(af[mi], b2[ni], y2[mi][ni], 0, 0, 0);
          }
      }
      #pragma unroll
      for (int mi = 0; mi < 2; ++mi)
        #pragma unroll
        for (int ni = 0; ni < 2; ++ni) {
          int nl = wr * 32 + mi * 16 + lq * 4;
          int e  = wc * 32 + ni * 16 + l15;
          #pragma unroll
          for (int r = 0; r < 4; ++r) {
            float a1 = y1[mi][ni][r], a2 = y2[mi][ni][r];
            float sg = 1.0f / (1.0f + __expf(-a2));
            concat[(rowb + n0 + nl + r) * (size_t)CCP + h * D_ + e] = (__bf16)(a1 * (a2 * sg));
          }
        }
      __syncthreads();
    }
  } else {
    // ---------- dwc_apply (fused grad-reduce + norm + conv) ----------
    const int blk = blockIdx.x;
    const int b = blk / 12, sp = blk - b * 12;
    const int dd = tid & 63, rl = tid >> 6;
    for (int i = tid; i < 9600; i += 256) ((unsigned*)u.da.qS)[i] = 0u;
    __syncthreads();
    const size_t base = (size_t)b * N_ * NPAD;
    for (int i = tid; i < 6 * 48 * 8; i += 256) {
      int y6 = i / 384; int rem = i - y6 * 384; int x = rem >> 3; int c8 = rem & 7;
      int y = 4 * sp - 1 + y6;
      if (y >= 0 && y < 48) {
        int p = y * 48 + x;
        bf16x8 v = *(const bf16x8*)&qkv[base + (size_t)p * NPAD + 2304 + c8 * 8];
        *(bf16x8*)&u.da.qS[((y6 * 50) + x + 1) * 64 + c8 * 8] = v;
      }
    }
    float g[9];
    #pragma unroll
    for (int j = 0; j < 9; ++j) g[j] = 0.f;
    for (int s = 0; s < 12; ++s)
      #pragma unroll
      for (int j = 0; j < 9; ++j)
        g[j] += w3p[((size_t)(b * 12 + s) * 64 + dd) * 9 + j];
    float ss = 0.f;
    #pragma unroll
    for (int j = 0; j < 9; ++j) ss += g[j] * g[j];
    float rn = 1.0f / (sqrtf(ss) + 1.0f);
    float wv[9];
    #pragma unroll
    for (int j = 0; j < 9; ++j) wv[j] = w3[dd * 9 + j] - g[j] * rn;
    __syncthreads();
    const int y = 4 * sp + rl;
    for (int x = 0; x < 48; ++x) {
      float s = 0.f;
      #pragma unroll
      for (int j = 0; j < 9; ++j) {
        int ys = j / 3, xs = j - ys * 3;
        s += (float)u.da.qS[((rl + ys) * 50 + x + xs) * 64 + dd] * wv[j];
      }
      int p = y * 48 + x;
      concat[((size_t)b * N_ + p) * CCP + 768 + dd] = (__bf16)s;
    }
  }
}

// ---------------- launcher ----------------
extern "C" void kernel_launch(void* const* d_in, const int* in_sizes, int n_in,
                              void* d_out, int out_size, void* d_ws, size_t ws_size,
                              hipStream_t stream) {
  const float* x      = (const float*)d_in[0];
  const float* qkv_w  = (const float*)d_in[1];
  const float* qkv_b  = (const float*)d_in[2];
  const float* w1     = (const float*)d_in[3];
  const float* w2     = (const float*)d_in[4];
  const float* w3     = (const float*)d_in[5];
  const float* proj_w = (const float*)d_in[6];
  const float* proj_b = (const float*)d_in[7];

  char* ws = (char*)d_ws;
  __bf16* xb     = (__bf16*)ws;                     // 56,623,104 B (dead after QKV)
  __bf16* wqkvb  = (__bf16*)(ws + 56623104);        //  3,932,160 B
  float*  qkvbp  = (float*) (ws + 60555264);        //     10,240 B
  __bf16* concat = (__bf16*)ws;                     // 61,341,696 B (reuse, stride 832)
  __bf16* qkvb16 = (__bf16*)(ws + 66060288);        // 188,743,680 B
  __bf16* pwb    = (__bf16*)(ws + 254803968);       //  1,277,952 B
  float*  w3p    = (float*) (ws + 256217088);       //    442,368 B
  float*  gpart  = (float*) (ws + 256659456);       // 25,165,824 B
  __bf16* wu     = (__bf16*)(ws + 281825280);       //  3,145,728 B

  cvt_all<<<15096, 256, 0, stream>>>(x, qkv_w, qkv_b, proj_w, xb, wqkvb, qkvbp, pwb);

  // QKV GEMM: [36864 x 768] @ [768 x 2560] -> grid 144*10 = 1440, KT=12
  gemm8<0><<<1440, 512, 0, stream>>>(xb, wqkvb, qkvbp, (void*)qkvb16,
                                     768, NPAD, 10, 12);

  grad_combo <<< 960, 256, 0, stream>>>(qkvb16, w1, w2, gpart, w3p);
  inner_upd  <<< 192, 256, 0, stream>>>(gpart, w1, w2, wu);
  apply_combo<<<1344, 256, 0, stream>>>(qkvb16, wu, w3p, w3, concat);

  // proj GEMM: [36864 x 832] @ [832 x 768] -> grid 144*3 = 432, KT=13
  gemm8<1><<<432, 512, 0, stream>>>(concat, pwb, proj_b, d_out,
                                    832, 768, 3, 13);
}